// Round 24
// baseline (205.501 us; speedup 1.0000x reference)
//
#include <hip/hip_runtime.h>

// CrossAttention: B=16, Sq=4096, Dm=512, Skv=77, Dc=768, H=8, Dh=64, inner=512
// Single-pass fp16 MFMA pipeline.
//   0. prep2   : FAT launch. Blocks 0..319: merged k+v projection (64x64,
//                BK=64 dbuf, Wk/Wv read DIRECT fp32 -> transpose-in-staging,
//                no WkT/WvT dependency). Blocks 320..2991: WqT/WoT
//                transposes + vT/kbuf pad zero. kv overlaps the transposes.
//   1. gemm_x16: q = x(fp32)@WqT -> fp16 (cvt fused, 128x256, R18 loop) (ws)
//   2. attn_h16: MFMA scores + in-reg fp32 softmax + MFMA PV           (ws)
//   3. gemm_h16: out = attn@WoT + bout -> fp32, 128x256 gl_lds dbuf  (d_out)

typedef unsigned short u16;
typedef unsigned int u32;
typedef _Float16 f16;
typedef __attribute__((ext_vector_type(8))) _Float16 half8;
typedef __attribute__((ext_vector_type(4))) _Float16 half4;
typedef __attribute__((ext_vector_type(4))) float f32x4;

__device__ __forceinline__ f32x4 mfma16h(half8 a, half8 b, f32x4 c) {
    return __builtin_amdgcn_mfma_f32_16x16x32_f16(a, b, c, 0, 0, 0);
}
// async global->LDS, 16B per lane; LDS dest = wave-uniform base + lane*16
__device__ __forceinline__ void gl_lds16(const f16* g, f16* l) {
    __builtin_amdgcn_global_load_lds(
        (const __attribute__((address_space(1))) void*)g,
        (__attribute__((address_space(3))) void*)l, 16, 0, 0);
}

// ---------------- prep2: kv projection + transposes + pads, one launch ------
// kv blocks first (long poles, start at t=0); transposes/pads fill the rest.
__global__ __launch_bounds__(256) void prep2(
    const float* __restrict__ ctx, const float* __restrict__ Wk,
    const float* __restrict__ Wv, const float* __restrict__ Wq,
    const float* __restrict__ Wo,
    f16* __restrict__ WqT, f16* __restrict__ WoT,
    f16* __restrict__ kbuf, f16* __restrict__ vT)
{
    __shared__ f16 lA[2][64 * 72];   // kv path only (36 KB total)
    __shared__ f16 lB[2][64 * 72];

    const int bid = blockIdx.x;
    const int t = threadIdx.x;

    if (bid < 320) {
        // ----- kv path: 64x64 tile, BK=64, issue-early reg-staged dbuf -----
        const int lane = t & 63;
        const int w = t >> 6;
        const int ar = lane & 15;
        const int kc = (lane >> 4) << 3;
        const int wr = w >> 1, wc = w & 1;
        const int m0 = (bid % 20) * 64, n0 = (bid / 20) * 64;

        const float* Wsel = (n0 < 512) ? Wk : Wv;
        const int srow = t >> 2;          // 0..63 (n within tile / A row)
        const int sc   = (t & 3) << 4;    // k-offset 0,16,32,48
        const int ncol = (n0 & 511) + srow;

        f32x4 acc[2][2] = {};
        f32x4 rA[4];
        float rBv[16];

        auto LOAD_KV = [&](int kt) {
            const int gr = m0 + srow;
            if (gr < 1232) {
                const float* pa = ctx + (size_t)gr * 768 + (kt << 6) + sc;
                #pragma unroll
                for (int j = 0; j < 4; ++j) rA[j] = *(const f32x4*)(pa + j * 4);
            } else {
                #pragma unroll
                for (int j = 0; j < 4; ++j) rA[j] = (f32x4){0.f, 0.f, 0.f, 0.f};
            }
            // B[n][k] = Wsel[k*512 + ncol]; 16 scalar loads, 4x64B-coalesced
            const float* pw = Wsel + (size_t)((kt << 6) + sc) * 512 + ncol;
            #pragma unroll
            for (int j = 0; j < 16; ++j) rBv[j] = pw[(size_t)j * 512];
        };
        auto WRITE_KV = [&](int buf) {
            half8 h0 = { (f16)rA[0].x, (f16)rA[0].y, (f16)rA[0].z, (f16)rA[0].w,
                         (f16)rA[1].x, (f16)rA[1].y, (f16)rA[1].z, (f16)rA[1].w };
            half8 h1 = { (f16)rA[2].x, (f16)rA[2].y, (f16)rA[2].z, (f16)rA[2].w,
                         (f16)rA[3].x, (f16)rA[3].y, (f16)rA[3].z, (f16)rA[3].w };
            *(half8*)(&lA[buf][srow * 72 + sc])     = h0;
            *(half8*)(&lA[buf][srow * 72 + sc + 8]) = h1;
            half8 b0 = { (f16)rBv[0], (f16)rBv[1], (f16)rBv[2], (f16)rBv[3],
                         (f16)rBv[4], (f16)rBv[5], (f16)rBv[6], (f16)rBv[7] };
            half8 b1 = { (f16)rBv[8],  (f16)rBv[9],  (f16)rBv[10], (f16)rBv[11],
                         (f16)rBv[12], (f16)rBv[13], (f16)rBv[14], (f16)rBv[15] };
            *(half8*)(&lB[buf][srow * 72 + sc])     = b0;
            *(half8*)(&lB[buf][srow * 72 + sc + 8]) = b1;
        };

        LOAD_KV(0);
        WRITE_KV(0);
        __syncthreads();

        int cur = 0;
        for (int kt = 0; kt < 12; ++kt) {
            if (kt + 1 < 12) LOAD_KV(kt + 1);   // issue-early: flies under MFMA

            #pragma unroll
            for (int ks = 0; ks < 2; ++ks) {
                half8 fa[2], fb[2];
                #pragma unroll
                for (int m = 0; m < 2; ++m)
                    fa[m] = *(const half8*)(&lA[cur][(wr * 32 + m * 16 + ar) * 72
                                                     + ks * 32 + kc]);
                #pragma unroll
                for (int n = 0; n < 2; ++n)
                    fb[n] = *(const half8*)(&lB[cur][(wc * 32 + n * 16 + ar) * 72
                                                     + ks * 32 + kc]);
                #pragma unroll
                for (int m = 0; m < 2; ++m)
                    #pragma unroll
                    for (int n = 0; n < 2; ++n)
                        acc[m][n] = mfma16h(fa[m], fb[n], acc[m][n]);
            }

            if (kt + 1 < 12) WRITE_KV(cur ^ 1);  // vmcnt wait lands here
            __syncthreads();
            cur ^= 1;
        }

        #pragma unroll
        for (int n = 0; n < 2; ++n) {
            int col = n0 + wc * 32 + n * 16 + ar;
            #pragma unroll
            for (int m = 0; m < 2; ++m) {
                #pragma unroll
                for (int r = 0; r < 4; ++r) {
                    int row = m0 + wr * 32 + m * 16 + ((lane >> 4) << 2) + r;
                    if (row < 1232) {
                        f16 v = (f16)acc[m][n][r];
                        if (col < 512) {
                            kbuf[(size_t)row * 512 + col] = v;
                        } else {
                            int bb = row / 77;
                            int si = row - bb * 77;
                            vT[((size_t)bb * 512 + (col - 512)) * 96 + si] = v;
                        }
                    }
                }
            }
        }
        return;
    }

    // ----- transpose WqT/WoT + pad zeroing -----
    int idx = (bid - 320) * 256 + t;
    if (idx < 262144) {
        int n = idx / 512, k = idx - n * 512;
        WqT[idx] = (f16)Wq[(size_t)k * 512 + n];
        return;
    }
    idx -= 262144;
    if (idx < 262144) {
        int n = idx / 512, k = idx - n * 512;
        WoT[idx] = (f16)Wo[(size_t)k * 512 + n];
        return;
    }
    idx -= 262144;
    const int nv = 16 * 512 * 19;
    if (idx < nv) {
        int g = idx / 19, s = idx - g * 19;
        vT[(size_t)g * 96 + 77 + s] = (f16)0.f;
    } else {
        int j = idx - nv;
        if (j < 8 * 512) kbuf[(size_t)1232 * 512 + j] = (f16)0.f;
    }
}

// ---------------- q-proj GEMM: fused fp32->fp16, 128x256 tile (R18) --------
// A fp32 [M][K], B fp16 [N][K]; grid dim3(2, 512), block 256.
__global__ __launch_bounds__(256, 2) void gemm_x16(
    const float* __restrict__ A, const f16* __restrict__ B,
    f16* __restrict__ CHalf, int M, int N, int K)
{
    __shared__ f16 sA[2][128 * 32];
    __shared__ f16 sB[2][256 * 32];

    const int t = threadIdx.x;
    const int lane = t & 63;
    const int w = t >> 6;
    const int wr = w >> 1, wc = w & 1;

    const int f = blockIdx.x + gridDim.x * blockIdx.y;
    const int cpx = (gridDim.x * gridDim.y) >> 3;
    const int logical = (f & 7) * cpx + (f >> 3);
    const int m0 = (logical / gridDim.x) * 128;
    const int n0 = (logical % gridDim.x) * 256;

    const int ar = lane & 15;
    const int kc = (lane >> 4) << 3;

    // A staging (coalesced): row (t>>3)+j*32, f32 col (t&7)*4
    const int arow = t >> 3;
    const int acol = (t & 7) << 2;
    const int brow = lane >> 2;
    const int bcol = (lane & 3) << 3;

    f32x4 acc[4][8] = {};
    f32x4 rA[4];

    auto LOAD_A = [&](int kt) {
        #pragma unroll
        for (int j = 0; j < 4; ++j)
            rA[j] = *(const f32x4*)(A + (size_t)(m0 + arow + j * 32) * K
                                      + (kt << 5) + acol);
    };
    auto WRITE_A = [&](int buf) {
        #pragma unroll
        for (int j = 0; j < 4; ++j) {
            half4 h = {(f16)rA[j].x, (f16)rA[j].y, (f16)rA[j].z, (f16)rA[j].w};
            *(half4*)(&sA[buf][(arow + j * 32) * 32 + acol]) = h;
        }
    };
    auto STAGE_B = [&](int buf, int kt) {
        #pragma unroll
        for (int j = 0; j < 4; ++j) {
            const int ci = w * 4 + j;
            gl_lds16(B + (size_t)(n0 + ci * 16 + brow) * K + (kt << 5) + bcol,
                     &sB[buf][ci * 512]);
        }
    };

    const int nk = K >> 5;
    LOAD_A(0);
    STAGE_B(0, 0);
    WRITE_A(0);
    __syncthreads();

    int cur = 0;
    for (int kt = 0; kt < nk; ++kt) {
        if (kt + 1 < nk) {
            LOAD_A(kt + 1);
            STAGE_B(cur ^ 1, kt + 1);
        }

        half8 fa[4], fb[8];
        #pragma unroll
        for (int m = 0; m < 4; ++m)
            fa[m] = *(const half8*)(&sA[cur][(wr * 64 + m * 16 + ar) * 32 + kc]);
        #pragma unroll
        for (int n = 0; n < 8; ++n)
            fb[n] = *(const half8*)(&sB[cur][(wc * 128 + n * 16 + ar) * 32 + kc]);

        __builtin_amdgcn_s_setprio(1);
        #pragma unroll
        for (int m = 0; m < 4; ++m)
            #pragma unroll
            for (int n = 0; n < 8; ++n)
                acc[m][n] = mfma16h(fa[m], fb[n], acc[m][n]);
        __builtin_amdgcn_s_setprio(0);

        if (kt + 1 < nk) WRITE_A(cur ^ 1);   // vmcnt wait lands after MFMA
        __syncthreads();
        cur ^= 1;
    }

    #pragma unroll
    for (int n = 0; n < 8; ++n) {
        int col = n0 + wc * 128 + n * 16 + ar;
        #pragma unroll
        for (int m = 0; m < 4; ++m) {
            #pragma unroll
            for (int r = 0; r < 4; ++r) {
                int row = m0 + wr * 64 + m * 16 + ((lane >> 4) << 2) + r;
                CHalf[(size_t)row * N + col] = (f16)acc[m][n][r];
            }
        }
    }
}

// ---------------- out-proj GEMM: fp16, 128x256 tile, gl_lds dbuf (R15) -----
__global__ __launch_bounds__(256, 2) void gemm_h16(
    const f16* __restrict__ A, const f16* __restrict__ B,
    const float* __restrict__ bias, float* __restrict__ C,
    int M, int N, int K)
{
    __shared__ f16 sA[2][128 * 32];
    __shared__ f16 sB[2][256 * 32];

    const int t = threadIdx.x;
    const int lane = t & 63;
    const int w = t >> 6;
    const int wr = w >> 1, wc = w & 1;

    const int f = blockIdx.x + gridDim.x * blockIdx.y;
    const int cpx = (gridDim.x * gridDim.y) >> 3;
    const int logical = (f & 7) * cpx + (f >> 3);
    const int m0 = (logical / gridDim.x) * 128;
    const int n0 = (logical % gridDim.x) * 256;

    const int ar = lane & 15;
    const int kc = (lane >> 4) << 3;
    const int srow = lane >> 2;
    const int scol = (lane & 3) << 3;

    f32x4 acc[4][8] = {};

    auto STAGE = [&](int buf, int kt) {
        #pragma unroll
        for (int j = 0; j < 2; ++j) {
            const int ci = w * 2 + j;
            gl_lds16(A + (size_t)(m0 + ci * 16 + srow) * K + (kt << 5) + scol,
                     &sA[buf][ci * 512]);
        }
        #pragma unroll
        for (int j = 0; j < 4; ++j) {
            const int ci = w * 4 + j;
            gl_lds16(B + (size_t)(n0 + ci * 16 + srow) * K + (kt << 5) + scol,
                     &sB[buf][ci * 512]);
        }
    };

    const int nk = K >> 5;
    STAGE(0, 0);
    __syncthreads();

    int cur = 0;
    for (int kt = 0; kt < nk; ++kt) {
        if (kt + 1 < nk) STAGE(cur ^ 1, kt + 1);

        half8 fa[4], fb[8];
        #pragma unroll
        for (int m = 0; m < 4; ++m)
            fa[m] = *(const half8*)(&sA[cur][(wr * 64 + m * 16 + ar) * 32 + kc]);
        #pragma unroll
        for (int n = 0; n < 8; ++n)
            fb[n] = *(const half8*)(&sB[cur][(wc * 128 + n * 16 + ar) * 32 + kc]);

        __builtin_amdgcn_s_setprio(1);
        #pragma unroll
        for (int m = 0; m < 4; ++m)
            #pragma unroll
            for (int n = 0; n < 8; ++n)
                acc[m][n] = mfma16h(fa[m], fb[n], acc[m][n]);
        __builtin_amdgcn_s_setprio(0);
        __syncthreads();
        cur ^= 1;
    }

    #pragma unroll
    for (int n = 0; n < 8; ++n) {
        int col = n0 + wc * 128 + n * 16 + ar;
        float bv = bias[col];
        #pragma unroll
        for (int m = 0; m < 4; ++m) {
            #pragma unroll
            for (int r = 0; r < 4; ++r) {
                int row = m0 + wr * 64 + m * 16 + ((lane >> 4) << 2) + r;
                C[(size_t)row * N + col] = acc[m][n][r] + bv;
            }
        }
    }
}

// ---------------- MFMA attention (fp16 inputs, fp32 softmax) ----------------
// grid (Sq/128, H, B), block 256 (4 waves, 32 q-rows each); P wave-private.
__global__ __launch_bounds__(256) void attn_h16(
    const f16* __restrict__ q, const f16* __restrict__ k,
    const f16* __restrict__ vT, f16* __restrict__ outA)
{
    constexpr int PST = 104;
    __shared__ f16 sP[4 * 32 * PST];

    const int t = threadIdx.x;
    const int lane = t & 63;
    const int w = t >> 6;
    const int ar = lane & 15;
    const int kg = lane >> 4;
    const int kc = kg << 3;
    const int b = blockIdx.z, head = blockIdx.y;
    const size_t qrow0 = (size_t)b * 4096 + blockIdx.x * 128 + w * 32;

    f32x4 accs[2][5] = {};
    #pragma unroll
    for (int ks = 0; ks < 2; ++ks) {
        const int d = head * 64 + ks * 32 + kc;
        half8 ah[2];
        #pragma unroll
        for (int m = 0; m < 2; ++m)
            ah[m] = *(const half8*)(q + (qrow0 + m * 16 + ar) * 512 + d);
        #pragma unroll
        for (int n = 0; n < 5; ++n) {
            half8 bh = *(const half8*)(k + ((size_t)(b * 77 + n * 16 + ar)) * 512 + d);
            #pragma unroll
            for (int m = 0; m < 2; ++m)
                accs[m][n] = mfma16h(ah[m], bh, accs[m][n]);
        }
    }

    #pragma unroll
    for (int m = 0; m < 2; ++m) {
        #pragma unroll
        for (int r = 0; r < 4; ++r) {
            float mx = -1e30f;
            #pragma unroll
            for (int n = 0; n < 5; ++n) {
                float v = accs[m][n][r] * 0.125f;
                if (n == 4 && ar >= 13) v = -1e30f;
                accs[m][n][r] = v;
                mx = fmaxf(mx, v);
            }
            mx = fmaxf(mx, __shfl_xor(mx, 1));
            mx = fmaxf(mx, __shfl_xor(mx, 2));
            mx = fmaxf(mx, __shfl_xor(mx, 4));
            mx = fmaxf(mx, __shfl_xor(mx, 8));
            float sum = 0.f;
            #pragma unroll
            for (int n = 0; n < 5; ++n) {
                float e = __expf(accs[m][n][r] - mx);
                accs[m][n][r] = e;
                sum += e;
            }
            sum += __shfl_xor(sum, 1);
            sum += __shfl_xor(sum, 2);
            sum += __shfl_xor(sum, 4);
            sum += __shfl_xor(sum, 8);
            float inv = 1.f / sum;
            #pragma unroll
            for (int n = 0; n < 5; ++n) accs[m][n][r] *= inv;
        }
    }

    f16* myP = sP + w * 32 * PST;
    for (int i = lane; i < 32 * 12; i += 64) {
        int row = i / 12, c = 80 + (i % 12) * 2;
        *(u32*)(myP + row * PST + c) = 0;
    }
    #pragma unroll
    for (int m = 0; m < 2; ++m)
        #pragma unroll
        for (int n = 0; n < 5; ++n)
            #pragma unroll
            for (int r = 0; r < 4; ++r)
                myP[(m * 16 + kg * 4 + r) * PST + n * 16 + ar] = (f16)accs[m][n][r];

    f32x4 accp[2][4] = {};
    #pragma unroll
    for (int ks = 0; ks < 3; ++ks) {
        half8 pa[2];
        #pragma unroll
        for (int m = 0; m < 2; ++m)
            pa[m] = *(const half8*)(myP + (m * 16 + ar) * PST + ks * 32 + kc);
        #pragma unroll
        for (int n = 0; n < 4; ++n) {
            half8 bh = *(const half8*)(vT + ((size_t)b * 512 + head * 64 + n * 16 + ar) * 96 + ks * 32 + kc);
            #pragma unroll
            for (int m = 0; m < 2; ++m)
                accp[m][n] = mfma16h(pa[m], bh, accp[m][n]);
        }
    }

    #pragma unroll
    for (int m = 0; m < 2; ++m)
        #pragma unroll
        for (int n = 0; n < 4; ++n)
            #pragma unroll
            for (int r = 0; r < 4; ++r)
                outA[(qrow0 + m * 16 + kg * 4 + r) * 512 + head * 64 + n * 16 + ar]
                    = (f16)accp[m][n][r];
}

extern "C" void kernel_launch(void* const* d_in, const int* in_sizes, int n_in,
                              void* d_out, int out_size, void* d_ws, size_t ws_size,
                              hipStream_t stream)
{
    const float* x    = (const float*)d_in[0];   // [16,4096,512]
    const float* ctx  = (const float*)d_in[1];   // [16,77,768]
    const float* Wq   = (const float*)d_in[2];   // [512,512]
    const float* Wk   = (const float*)d_in[3];   // [768,512]
    const float* Wv   = (const float*)d_in[4];   // [768,512]
    const float* Wout = (const float*)d_in[5];   // [512,512]
    const float* bout = (const float*)d_in[6];   // [512]

    char* ws = (char*)d_ws;
    size_t off = 0;
    auto alloc = [&](size_t bytes) -> void* {
        void* p = ws + off;
        off += (bytes + 255) & ~(size_t)255;
        return p;
    };
    f16* WqT = (f16*)alloc(512 * 512 * 2);
    f16* WoT = (f16*)alloc(512 * 512 * 2);
    f16* kbuf = (f16*)alloc((size_t)1240 * 512 * 2);
    f16* vT   = (f16*)alloc((size_t)16 * 512 * 96 * 2);
    f16* qh   = (f16*)alloc((size_t)65536 * 512 * 2);
    f16* attnA = (f16*)alloc((size_t)65536 * 512 * 2);
    (void)ws_size; (void)in_sizes; (void)n_in; (void)out_size;

    // 0. kv projection (direct fp32 weights) + transposes + pads, one launch
    prep2<<<dim3(2992), dim3(256), 0, stream>>>(
        ctx, Wk, Wv, Wq, Wout, WqT, WoT, kbuf, vT);

    // 1. q projection (cvt fused), 128x256
    gemm_x16<<<dim3(2, 512), dim3(256), 0, stream>>>(
        x, WqT, qh, 65536, 512, 512);

    // 2. attention
    attn_h16<<<dim3(32, 8, 16), dim3(256), 0, stream>>>(qh, kbuf, vT, attnA);

    // 3. output projection + bias -> d_out fp32, 128x256
    gemm_h16<<<dim3(2, 512), dim3(256), 0, stream>>>(
        attnA, WoT, bout, (float*)d_out, 65536, 512, 512);
}

// Round 25
// 199.802 us; speedup vs baseline: 1.0285x; 1.0285x over previous
//
#include <hip/hip_runtime.h>

// CrossAttention: B=16, Sq=4096, Dm=512, Skv=77, Dc=768, H=8, Dh=64, inner=512
// Single-pass fp16 MFMA pipeline (R23 = session best, 200.1 us).
//   0. prep : weight transposes -> fp16 + vT/kbuf pad zero (one launch)
//   1. kvx  : FAT kernel, single 48KB LDS pool.
//             Blocks 0..1023:  q = x@Wq (128x256, R18 loop).
//             Blocks 1024..1343: merged k+v projection (64x64, BK=64 dbuf)
//             -- kv in the tail so q-proj starts at full occupancy.
//   2. attn_h16 : MFMA scores + in-reg fp32 softmax + MFMA PV        (ws)
//   3. gemm_h16 : out = attn@Wout + bout -> fp32, 128x256 gl_lds dbuf (d_out)

typedef unsigned short u16;
typedef unsigned int u32;
typedef _Float16 f16;
typedef __attribute__((ext_vector_type(8))) _Float16 half8;
typedef __attribute__((ext_vector_type(4))) _Float16 half4;
typedef __attribute__((ext_vector_type(4))) float f32x4;

__device__ __forceinline__ f32x4 mfma16h(half8 a, half8 b, f32x4 c) {
    return __builtin_amdgcn_mfma_f32_16x16x32_f16(a, b, c, 0, 0, 0);
}
// async global->LDS, 16B per lane; LDS dest = wave-uniform base + lane*16
__device__ __forceinline__ void gl_lds16(const f16* g, f16* l) {
    __builtin_amdgcn_global_load_lds(
        (const __attribute__((address_space(1))) void*)g,
        (__attribute__((address_space(3))) void*)l, 16, 0, 0);
}

// ---------------- prep: 4 weight transposes + pad zeroing, one launch -------
__global__ __launch_bounds__(256) void prep(
    const float* __restrict__ Wq, const float* __restrict__ Wk,
    const float* __restrict__ Wv, const float* __restrict__ Wo,
    f16* __restrict__ WqT, f16* __restrict__ WkT,
    f16* __restrict__ WvT, f16* __restrict__ WoT,
    f16* __restrict__ vT, f16* __restrict__ kbuf)
{
    int idx = blockIdx.x * 256 + threadIdx.x;
    if (idx < 1310720) {
        const float* W; f16* T; int K; int base;
        if (idx < 262144)        { W = Wq; T = WqT; K = 512; base = 0; }
        else if (idx < 655360)   { W = Wk; T = WkT; K = 768; base = 262144; }
        else if (idx < 1048576)  { W = Wv; T = WvT; K = 768; base = 655360; }
        else                     { W = Wo; T = WoT; K = 512; base = 1048576; }
        int j = idx - base;
        int n = j / K, k = j - n * K;
        T[j] = (f16)W[(size_t)k * 512 + n];
        return;
    }
    int i = idx - 1310720;
    const int nv = 16 * 512 * 19;
    if (i < nv) {
        int g = i / 19, s = i - g * 19;
        vT[(size_t)g * 96 + 77 + s] = (f16)0.f;
    } else {
        int j = i - nv;
        if (j < 8 * 512) kbuf[(size_t)1232 * 512 + j] = (f16)0.f;
    }
}

// ---------------- FAT kernel: q-proj (blocks 0..1023) + kv tail -------------
// Single 48KB LDS pool; kv path uses 36KB (BK=64 dbuf), q path full pool.
__global__ __launch_bounds__(256, 2) void kvx(
    const float* __restrict__ ctx, const f16* __restrict__ Bkv,
    f16* __restrict__ kbuf, f16* __restrict__ vT,
    const float* __restrict__ x, const f16* __restrict__ WqT,
    f16* __restrict__ qh)
{
    __shared__ f16 smem[24576];   // 49152 B shared by both paths

    const int bid = blockIdx.x;
    const int t = threadIdx.x;
    const int lane = t & 63;
    const int w = t >> 6;
    const int ar = lane & 15;
    const int kc = (lane >> 4) << 3;

    if (bid >= 1024) {
        // ----- kv path (tail): 64x64 tile, BK=64, issue-early dbuf -----
        f16* lA = smem;               // [2][64*72] -> buf*4608
        f16* lB = smem + 9216;        // [2][64*72] -> buf*4608 (36KB total)

        const int kb = bid - 1024;
        const int wr = w >> 1, wc = w & 1;
        const int m0 = (kb % 20) * 64, n0 = (kb / 20) * 64;

        const int srow = t >> 2;          // 0..63
        const int sc   = (t & 3) << 4;    // f16/f32 col 0,16,32,48

        f32x4 acc[2][2] = {};
        f32x4 rA[4];
        half8 rB[2];

        auto LOAD_KV = [&](int kt) {
            const int gr = m0 + srow;
            if (gr < 1232) {
                const float* pa = ctx + (size_t)gr * 768 + (kt << 6) + sc;
                #pragma unroll
                for (int j = 0; j < 4; ++j) rA[j] = *(const f32x4*)(pa + j * 4);
            } else {
                #pragma unroll
                for (int j = 0; j < 4; ++j) rA[j] = (f32x4){0.f, 0.f, 0.f, 0.f};
            }
            const f16* pb = Bkv + (size_t)(n0 + srow) * 768 + (kt << 6) + sc;
            rB[0] = *(const half8*)(pb);
            rB[1] = *(const half8*)(pb + 8);
        };
        auto WRITE_KV = [&](int buf) {
            half8 h0 = { (f16)rA[0].x, (f16)rA[0].y, (f16)rA[0].z, (f16)rA[0].w,
                         (f16)rA[1].x, (f16)rA[1].y, (f16)rA[1].z, (f16)rA[1].w };
            half8 h1 = { (f16)rA[2].x, (f16)rA[2].y, (f16)rA[2].z, (f16)rA[2].w,
                         (f16)rA[3].x, (f16)rA[3].y, (f16)rA[3].z, (f16)rA[3].w };
            *(half8*)(lA + buf * 4608 + srow * 72 + sc)     = h0;
            *(half8*)(lA + buf * 4608 + srow * 72 + sc + 8) = h1;
            *(half8*)(lB + buf * 4608 + srow * 72 + sc)     = rB[0];
            *(half8*)(lB + buf * 4608 + srow * 72 + sc + 8) = rB[1];
        };

        LOAD_KV(0);
        WRITE_KV(0);
        __syncthreads();

        int cur = 0;
        for (int kt = 0; kt < 12; ++kt) {
            if (kt + 1 < 12) LOAD_KV(kt + 1);   // issue-early: flies under MFMA

            #pragma unroll
            for (int ks = 0; ks < 2; ++ks) {
                half8 fa[2], fb[2];
                #pragma unroll
                for (int m = 0; m < 2; ++m)
                    fa[m] = *(const half8*)(lA + cur * 4608
                                + (wr * 32 + m * 16 + ar) * 72 + ks * 32 + kc);
                #pragma unroll
                for (int n = 0; n < 2; ++n)
                    fb[n] = *(const half8*)(lB + cur * 4608
                                + (wc * 32 + n * 16 + ar) * 72 + ks * 32 + kc);
                #pragma unroll
                for (int m = 0; m < 2; ++m)
                    #pragma unroll
                    for (int n = 0; n < 2; ++n)
                        acc[m][n] = mfma16h(fa[m], fb[n], acc[m][n]);
            }

            if (kt + 1 < 12) WRITE_KV(cur ^ 1);  // vmcnt wait lands here
            __syncthreads();
            cur ^= 1;
        }

        #pragma unroll
        for (int n = 0; n < 2; ++n) {
            int col = n0 + wc * 32 + n * 16 + ar;
            #pragma unroll
            for (int m = 0; m < 2; ++m) {
                #pragma unroll
                for (int r = 0; r < 4; ++r) {
                    int row = m0 + wr * 32 + m * 16 + ((lane >> 4) << 2) + r;
                    if (row < 1232) {
                        f16 v = (f16)acc[m][n][r];
                        if (col < 512) {
                            kbuf[(size_t)row * 512 + col] = v;
                        } else {
                            int bb = row / 77;
                            int si = row - bb * 77;
                            vT[((size_t)bb * 512 + (col - 512)) * 96 + si] = v;
                        }
                    }
                }
            }
        }
        return;
    }

    // ---------- q-projection path (R18 gemm_x16, 128x256 tile) ----------
    f16* sA0 = smem;            // [2][128*32] -> buf*4096
    f16* sB0 = smem + 8192;     // [2][256*32] -> buf*8192

    const int wr = w >> 1, wc = w & 1;

    // XCD-chunked bijective swizzle over 1024 q-blocks (%8==0)
    const int f = bid;
    const int logical = (f & 7) * 128 + (f >> 3);
    const int m0 = (logical >> 1) * 128;
    const int n0 = (logical & 1) * 256;

    // A staging (coalesced): row (t>>3)+j*32, f32 col (t&7)*4
    const int arow = t >> 3;
    const int acol = (t & 7) << 2;
    const int brow = lane >> 2;
    const int bcol = (lane & 3) << 3;

    f32x4 acc[4][8] = {};
    f32x4 rA[4];

    auto LOAD_A = [&](int kt) {
        #pragma unroll
        for (int j = 0; j < 4; ++j)
            rA[j] = *(const f32x4*)(x + (size_t)(m0 + arow + j * 32) * 512
                                      + (kt << 5) + acol);
    };
    auto WRITE_A = [&](int buf) {
        #pragma unroll
        for (int j = 0; j < 4; ++j) {
            half4 h = {(f16)rA[j].x, (f16)rA[j].y, (f16)rA[j].z, (f16)rA[j].w};
            *(half4*)(sA0 + buf * 4096 + (arow + j * 32) * 32 + acol) = h;
        }
    };
    auto STAGE_B = [&](int buf, int kt) {
        #pragma unroll
        for (int j = 0; j < 4; ++j) {
            const int ci = w * 4 + j;
            gl_lds16(WqT + (size_t)(n0 + ci * 16 + brow) * 512 + (kt << 5) + bcol,
                     sB0 + buf * 8192 + ci * 512);
        }
    };

    LOAD_A(0);
    STAGE_B(0, 0);
    WRITE_A(0);
    __syncthreads();

    int cur = 0;
    for (int kt = 0; kt < 16; ++kt) {
        if (kt + 1 < 16) {
            LOAD_A(kt + 1);
            STAGE_B(cur ^ 1, kt + 1);
        }

        half8 fa[4], fb[8];
        #pragma unroll
        for (int m = 0; m < 4; ++m)
            fa[m] = *(const half8*)(sA0 + cur * 4096 + (wr * 64 + m * 16 + ar) * 32 + kc);
        #pragma unroll
        for (int n = 0; n < 8; ++n)
            fb[n] = *(const half8*)(sB0 + cur * 8192 + (wc * 128 + n * 16 + ar) * 32 + kc);

        __builtin_amdgcn_s_setprio(1);
        #pragma unroll
        for (int m = 0; m < 4; ++m)
            #pragma unroll
            for (int n = 0; n < 8; ++n)
                acc[m][n] = mfma16h(fa[m], fb[n], acc[m][n]);
        __builtin_amdgcn_s_setprio(0);

        if (kt + 1 < 16) WRITE_A(cur ^ 1);   // vmcnt wait lands after MFMA
        __syncthreads();
        cur ^= 1;
    }

    #pragma unroll
    for (int n = 0; n < 8; ++n) {
        int col = n0 + wc * 128 + n * 16 + ar;
        #pragma unroll
        for (int m = 0; m < 4; ++m) {
            #pragma unroll
            for (int r = 0; r < 4; ++r) {
                int row = m0 + wr * 64 + m * 16 + ((lane >> 4) << 2) + r;
                qh[(size_t)row * 512 + col] = (f16)acc[m][n][r];
            }
        }
    }
}

// ---------------- out-proj GEMM: fp16, 128x256 tile, gl_lds dbuf (R15) -----
__global__ __launch_bounds__(256, 2) void gemm_h16(
    const f16* __restrict__ A, const f16* __restrict__ B,
    const float* __restrict__ bias, float* __restrict__ C,
    int M, int N, int K)
{
    __shared__ f16 sA[2][128 * 32];
    __shared__ f16 sB[2][256 * 32];

    const int t = threadIdx.x;
    const int lane = t & 63;
    const int w = t >> 6;
    const int wr = w >> 1, wc = w & 1;

    const int f = blockIdx.x + gridDim.x * blockIdx.y;
    const int cpx = (gridDim.x * gridDim.y) >> 3;
    const int logical = (f & 7) * cpx + (f >> 3);
    const int m0 = (logical / gridDim.x) * 128;
    const int n0 = (logical % gridDim.x) * 256;

    const int ar = lane & 15;
    const int kc = (lane >> 4) << 3;
    const int srow = lane >> 2;
    const int scol = (lane & 3) << 3;

    f32x4 acc[4][8] = {};

    auto STAGE = [&](int buf, int kt) {
        #pragma unroll
        for (int j = 0; j < 2; ++j) {
            const int ci = w * 2 + j;
            gl_lds16(A + (size_t)(m0 + ci * 16 + srow) * K + (kt << 5) + scol,
                     &sA[buf][ci * 512]);
        }
        #pragma unroll
        for (int j = 0; j < 4; ++j) {
            const int ci = w * 4 + j;
            gl_lds16(B + (size_t)(n0 + ci * 16 + srow) * K + (kt << 5) + scol,
                     &sB[buf][ci * 512]);
        }
    };

    const int nk = K >> 5;
    STAGE(0, 0);
    __syncthreads();

    int cur = 0;
    for (int kt = 0; kt < nk; ++kt) {
        if (kt + 1 < nk) STAGE(cur ^ 1, kt + 1);

        half8 fa[4], fb[8];
        #pragma unroll
        for (int m = 0; m < 4; ++m)
            fa[m] = *(const half8*)(&sA[cur][(wr * 64 + m * 16 + ar) * 32 + kc]);
        #pragma unroll
        for (int n = 0; n < 8; ++n)
            fb[n] = *(const half8*)(&sB[cur][(wc * 128 + n * 16 + ar) * 32 + kc]);

        __builtin_amdgcn_s_setprio(1);
        #pragma unroll
        for (int m = 0; m < 4; ++m)
            #pragma unroll
            for (int n = 0; n < 8; ++n)
                acc[m][n] = mfma16h(fa[m], fb[n], acc[m][n]);
        __builtin_amdgcn_s_setprio(0);
        __syncthreads();
        cur ^= 1;
    }

    #pragma unroll
    for (int n = 0; n < 8; ++n) {
        int col = n0 + wc * 128 + n * 16 + ar;
        float bv = bias[col];
        #pragma unroll
        for (int m = 0; m < 4; ++m) {
            #pragma unroll
            for (int r = 0; r < 4; ++r) {
                int row = m0 + wr * 64 + m * 16 + ((lane >> 4) << 2) + r;
                C[(size_t)row * N + col] = acc[m][n][r] + bv;
            }
        }
    }
}

// ---------------- MFMA attention (fp16 inputs, fp32 softmax) ----------------
// grid (Sq/128, H, B), block 256 (4 waves, 32 q-rows each); P wave-private.
__global__ __launch_bounds__(256) void attn_h16(
    const f16* __restrict__ q, const f16* __restrict__ k,
    const f16* __restrict__ vT, f16* __restrict__ outA)
{
    constexpr int PST = 104;
    __shared__ f16 sP[4 * 32 * PST];

    const int t = threadIdx.x;
    const int lane = t & 63;
    const int w = t >> 6;
    const int ar = lane & 15;
    const int kg = lane >> 4;
    const int kc = kg << 3;
    const int b = blockIdx.z, head = blockIdx.y;
    const size_t qrow0 = (size_t)b * 4096 + blockIdx.x * 128 + w * 32;

    f32x4 accs[2][5] = {};
    #pragma unroll
    for (int ks = 0; ks < 2; ++ks) {
        const int d = head * 64 + ks * 32 + kc;
        half8 ah[2];
        #pragma unroll
        for (int m = 0; m < 2; ++m)
            ah[m] = *(const half8*)(q + (qrow0 + m * 16 + ar) * 512 + d);
        #pragma unroll
        for (int n = 0; n < 5; ++n) {
            half8 bh = *(const half8*)(k + ((size_t)(b * 77 + n * 16 + ar)) * 512 + d);
            #pragma unroll
            for (int m = 0; m < 2; ++m)
                accs[m][n] = mfma16h(ah[m], bh, accs[m][n]);
        }
    }

    #pragma unroll
    for (int m = 0; m < 2; ++m) {
        #pragma unroll
        for (int r = 0; r < 4; ++r) {
            float mx = -1e30f;
            #pragma unroll
            for (int n = 0; n < 5; ++n) {
                float v = accs[m][n][r] * 0.125f;
                if (n == 4 && ar >= 13) v = -1e30f;
                accs[m][n][r] = v;
                mx = fmaxf(mx, v);
            }
            mx = fmaxf(mx, __shfl_xor(mx, 1));
            mx = fmaxf(mx, __shfl_xor(mx, 2));
            mx = fmaxf(mx, __shfl_xor(mx, 4));
            mx = fmaxf(mx, __shfl_xor(mx, 8));
            float sum = 0.f;
            #pragma unroll
            for (int n = 0; n < 5; ++n) {
                float e = __expf(accs[m][n][r] - mx);
                accs[m][n][r] = e;
                sum += e;
            }
            sum += __shfl_xor(sum, 1);
            sum += __shfl_xor(sum, 2);
            sum += __shfl_xor(sum, 4);
            sum += __shfl_xor(sum, 8);
            float inv = 1.f / sum;
            #pragma unroll
            for (int n = 0; n < 5; ++n) accs[m][n][r] *= inv;
        }
    }

    f16* myP = sP + w * 32 * PST;
    for (int i = lane; i < 32 * 12; i += 64) {
        int row = i / 12, c = 80 + (i % 12) * 2;
        *(u32*)(myP + row * PST + c) = 0;
    }
    #pragma unroll
    for (int m = 0; m < 2; ++m)
        #pragma unroll
        for (int n = 0; n < 5; ++n)
            #pragma unroll
            for (int r = 0; r < 4; ++r)
                myP[(m * 16 + kg * 4 + r) * PST + n * 16 + ar] = (f16)accs[m][n][r];

    f32x4 accp[2][4] = {};
    #pragma unroll
    for (int ks = 0; ks < 3; ++ks) {
        half8 pa[2];
        #pragma unroll
        for (int m = 0; m < 2; ++m)
            pa[m] = *(const half8*)(myP + (m * 16 + ar) * PST + ks * 32 + kc);
        #pragma unroll
        for (int n = 0; n < 4; ++n) {
            half8 bh = *(const half8*)(vT + ((size_t)b * 512 + head * 64 + n * 16 + ar) * 96 + ks * 32 + kc);
            #pragma unroll
            for (int m = 0; m < 2; ++m)
                accp[m][n] = mfma16h(pa[m], bh, accp[m][n]);
        }
    }

    #pragma unroll
    for (int m = 0; m < 2; ++m)
        #pragma unroll
        for (int n = 0; n < 4; ++n)
            #pragma unroll
            for (int r = 0; r < 4; ++r)
                outA[(qrow0 + m * 16 + kg * 4 + r) * 512 + head * 64 + n * 16 + ar]
                    = (f16)accp[m][n][r];
}

extern "C" void kernel_launch(void* const* d_in, const int* in_sizes, int n_in,
                              void* d_out, int out_size, void* d_ws, size_t ws_size,
                              hipStream_t stream)
{
    const float* x    = (const float*)d_in[0];   // [16,4096,512]
    const float* ctx  = (const float*)d_in[1];   // [16,77,768]
    const float* Wq   = (const float*)d_in[2];   // [512,512]
    const float* Wk   = (const float*)d_in[3];   // [768,512]
    const float* Wv   = (const float*)d_in[4];   // [768,512]
    const float* Wout = (const float*)d_in[5];   // [512,512]
    const float* bout = (const float*)d_in[6];   // [512]

    char* ws = (char*)d_ws;
    size_t off = 0;
    auto alloc = [&](size_t bytes) -> void* {
        void* p = ws + off;
        off += (bytes + 255) & ~(size_t)255;
        return p;
    };
    f16* WqT = (f16*)alloc(512 * 512 * 2);
    f16* WkT = (f16*)alloc(768 * 512 * 2);     // adjacent to WvT
    f16* WvT = (f16*)alloc(768 * 512 * 2);
    f16* WoT = (f16*)alloc(512 * 512 * 2);
    f16* kbuf = (f16*)alloc((size_t)1240 * 512 * 2);
    f16* vT   = (f16*)alloc((size_t)16 * 512 * 96 * 2);
    f16* qh   = (f16*)alloc((size_t)65536 * 512 * 2);
    f16* attnA = (f16*)alloc((size_t)65536 * 512 * 2);
    (void)ws_size; (void)in_sizes; (void)n_in; (void)out_size;

    // 0. weight transposes + pad zeroing (one launch)
    prep<<<dim3(5744), dim3(256), 0, stream>>>(
        Wq, Wk, Wv, Wout, WqT, WkT, WvT, WoT, vT, kbuf);

    // 1. FAT kernel: q projection (1024 blocks) + kv projection tail (320)
    kvx<<<dim3(1344), dim3(256), 0, stream>>>(
        ctx, WkT, kbuf, vT, x, WqT, qh);

    // 2. attention
    attn_h16<<<dim3(32, 8, 16), dim3(256), 0, stream>>>(qh, kbuf, vT, attnA);

    // 3. output projection + bias -> d_out fp32, 128x256
    gemm_h16<<<dim3(2, 512), dim3(256), 0, stream>>>(
        attnA, WoT, bout, (float*)d_out, 65536, 512, 512);
}